// Round 5
// baseline (903.051 us; speedup 1.0000x reference)
//
#include <hip/hip_runtime.h>

#define NVOX 500000
#define CIN 32
#define COUT 64
#define KK 27
#define EPSV 1e-5f
#define INVN (1.0f / 500000.0f)

typedef __bf16 bf16x8 __attribute__((ext_vector_type(8)));
typedef float f32x4 __attribute__((ext_vector_type(4)));

__device__ __forceinline__ float bf2f(ushort u) {
    return __uint_as_float(((unsigned)u) << 16);
}
__device__ __forceinline__ ushort f2bf(float f) {
    unsigned u = __float_as_uint(f);
    unsigned r = (u + 0x7FFFu + ((u >> 16) & 1u)) >> 16;  // RNE
    return (ushort)r;
}
union U4BF { uint4 u; bf16x8 b; ushort s[8]; };
__device__ __forceinline__ bf16x8 as_bf8(uint4 v) { U4BF c; c.u = v; return c.b; }
__device__ __forceinline__ bf16x8 f8_to_bf8(float4 a, float4 b) {
    U4BF c;
    c.s[0] = f2bf(a.x); c.s[1] = f2bf(a.y); c.s[2] = f2bf(a.z); c.s[3] = f2bf(a.w);
    c.s[4] = f2bf(b.x); c.s[5] = f2bf(b.y); c.s[6] = f2bf(b.z); c.s[7] = f2bf(b.w);
    return c.b;
}
// apply per-channel bn+relu to a gathered bf16x8 (as uint4), then repack to bf16; zero if !valid
__device__ __forceinline__ bf16x8 bn_frag(uint4 u, const float* a, const float* b, bool valid) {
    U4BF in; in.u = u;
    U4BF o;
#pragma unroll
    for (int j = 0; j < 8; j++) {
        float f = bf2f(in.s[j]);
        f = fmaxf(f * a[j] + b[j], 0.f);
        o.s[j] = f2bf(f);
    }
    if (!valid) { o.u.x = 0u; o.u.y = 0u; o.u.z = 0u; o.u.w = 0u; }
    return o.b;
}

// ---------------- prep: zero stats + y1 sentinel row, swizzle weights (f32 -> bf16 frags) --
// W1s layout: [k][nt][lane][8]  (B-frag 16x16x32: lane holds B[kk=(lane>>4)*8+j][n=nt*16+(lane&15)])
// W2s layout: [k][half][nt][lane][8]
// Wres_s:     [nt][lane][8]
__global__ void prep_kernel(const float* __restrict__ W1, const float* __restrict__ W2,
                            const float* __restrict__ Wres,
                            ushort* __restrict__ w1s, ushort* __restrict__ w2s,
                            ushort* __restrict__ wrs,
                            float* __restrict__ stats,
                            ushort* __restrict__ y1) {
    int t = blockIdx.x * 256 + threadIdx.x;
    if (t < 192) { stats[t] = 0.f; return; }
    if (t < 224) { y1[(size_t)NVOX * CIN + (t - 192)] = 0; return; }
    int d = t - 224;
    if (d < 27 * 4 * 64 * 8) {  // 55296
        int j = d & 7, lane = (d >> 3) & 63, nt = (d >> 9) & 3, k = d >> 11;
        int ci = ((lane >> 4) << 3) + j, co = (nt << 4) + (lane & 15);
        w1s[d] = f2bf(W1[(k * CIN + ci) * COUT + co]);
        return;
    }
    d -= 27 * 4 * 64 * 8;
    if (d < 27 * 2 * 4 * 64 * 8) {  // 110592
        int j = d & 7, lane = (d >> 3) & 63, nt = (d >> 9) & 3, half = (d >> 11) & 1, k = d >> 12;
        int ci = (half << 5) + ((lane >> 4) << 3) + j, co = (nt << 4) + (lane & 15);
        w2s[d] = f2bf(W2[(k * COUT + ci) * COUT + co]);
        return;
    }
    d -= 27 * 2 * 4 * 64 * 8;
    if (d < 4 * 64 * 8) {  // 2048
        int j = d & 7, lane = (d >> 3) & 63, nt = (d >> 9) & 3;
        int ci = ((lane >> 4) << 3) + j, co = (nt << 4) + (lane & 15);
        wrs[d] = f2bf(Wres[ci * COUT + co]);
    }
}

// ---------------- per-channel sum/sumsq over x (f32), x4 vectorized ----------------
__global__ void stats1_kernel(const float4* __restrict__ in, long long total4,
                              float* __restrict__ gsum, float* __restrict__ gsq) {
    __shared__ float s_sum[CIN];
    __shared__ float s_sq[CIN];
    int t = threadIdx.x;
    if (t < CIN) { s_sum[t] = 0.f; s_sq[t] = 0.f; }
    __syncthreads();
    long long i0 = (long long)blockIdx.x * blockDim.x + t;
    long long stride = (long long)gridDim.x * blockDim.x;
    int c0 = (int)((i0 * 4) & (CIN - 1));
    float ls0 = 0.f, ls1 = 0.f, ls2 = 0.f, ls3 = 0.f;
    float lq0 = 0.f, lq1 = 0.f, lq2 = 0.f, lq3 = 0.f;
    for (long long i = i0; i < total4; i += stride) {
        float4 v = in[i];
        ls0 += v.x; lq0 += v.x * v.x;
        ls1 += v.y; lq1 += v.y * v.y;
        ls2 += v.z; lq2 += v.z * v.z;
        ls3 += v.w; lq3 += v.w * v.w;
    }
    atomicAdd(&s_sum[c0 + 0], ls0); atomicAdd(&s_sq[c0 + 0], lq0);
    atomicAdd(&s_sum[c0 + 1], ls1); atomicAdd(&s_sq[c0 + 1], lq1);
    atomicAdd(&s_sum[c0 + 2], ls2); atomicAdd(&s_sq[c0 + 2], lq2);
    atomicAdd(&s_sum[c0 + 3], ls3); atomicAdd(&s_sq[c0 + 3], lq3);
    __syncthreads();
    if (t < CIN) {
        atomicAdd(&gsum[t], s_sum[t]);
        atomicAdd(&gsq[t], s_sq[t]);
    }
}

// ---------------- y1 = relu(bn1(x)), x4 vectorized, bf16 out ----------------
__global__ void bn1_kernel(const float4* __restrict__ in, ushort4* __restrict__ out,
                           long long total4,
                           const float* __restrict__ gsum, const float* __restrict__ gsq,
                           const float* __restrict__ gamma, const float* __restrict__ beta) {
    long long i0 = (long long)blockIdx.x * blockDim.x + threadIdx.x;
    long long stride = (long long)gridDim.x * blockDim.x;
    int c0 = (int)((i0 * 4) & (CIN - 1));
    float a[4], bb[4];
#pragma unroll
    for (int j = 0; j < 4; j++) {
        int c = c0 + j;
        float m = gsum[c] * INVN;
        float v = fmaxf(gsq[c] * INVN - m * m, 0.f);
        a[j] = gamma[c] * rsqrtf(v + EPSV);
        bb[j] = beta[c] - m * a[j];
    }
    for (long long i = i0; i < total4; i += stride) {
        float4 v = in[i];
        ushort4 o;
        o.x = f2bf(fmaxf(v.x * a[0] + bb[0], 0.f));
        o.y = f2bf(fmaxf(v.y * a[1] + bb[1], 0.f));
        o.z = f2bf(fmaxf(v.z * a[2] + bb[2], 0.f));
        o.w = f2bf(fmaxf(v.w * a[3] + bb[3], 0.f));
        out[i] = o;
    }
}

// ---------------- conv1: [N,32] -> [N,64], pipelined gathers, bf16 out + fused stats2 -----
__global__ __launch_bounds__(256) void conv1_kernel(const ushort* __restrict__ y1,
                                                    const int* __restrict__ nbr,
                                                    const ushort* __restrict__ w1s,
                                                    ushort* __restrict__ out1,
                                                    float* __restrict__ gsum2,
                                                    float* __restrict__ gsq2) {
    __shared__ float ss[COUT];
    __shared__ float sq[COUT];
    if (threadIdx.x < COUT) { ss[threadIdx.x] = 0.f; sq[threadIdx.x] = 0.f; }
    __syncthreads();

    const int lane = threadIdx.x & 63;
    const int wv = threadIdx.x >> 6;
    const int m = lane & 15, g = lane >> 4;
    const int rowbase = blockIdx.x * 64 + wv * 16;
    const int arow = rowbase + m;
    const bool av = arow < NVOX;
    const uint4* __restrict__ yv = (const uint4*)y1;
    const uint4* __restrict__ wvp = (const uint4*)w1s;

    int idxs[KK];
#pragma unroll
    for (int k = 0; k < KK; k++) {
        idxs[k] = av ? nbr[arow * KK + k] : NVOX;  // in [0,N]; row N of y1 is zeros
    }
    constexpr int P = 8;
    uint4 ga[P];
#pragma unroll
    for (int p = 0; p < P; p++) ga[p] = yv[idxs[p] * 4 + g];

    f32x4 acc0 = {0.f, 0.f, 0.f, 0.f}, acc1 = acc0, acc2 = acc0, acc3 = acc0;
#pragma unroll
    for (int k = 0; k < KK; k++) {
        bf16x8 a = as_bf8(ga[k % P]);
        if (k + P < KK) ga[k % P] = yv[idxs[k + P] * 4 + g];
        acc0 = __builtin_amdgcn_mfma_f32_16x16x32_bf16(a, as_bf8(wvp[(k * 4 + 0) * 64 + lane]), acc0, 0, 0, 0);
        acc1 = __builtin_amdgcn_mfma_f32_16x16x32_bf16(a, as_bf8(wvp[(k * 4 + 1) * 64 + lane]), acc1, 0, 0, 0);
        acc2 = __builtin_amdgcn_mfma_f32_16x16x32_bf16(a, as_bf8(wvp[(k * 4 + 2) * 64 + lane]), acc2, 0, 0, 0);
        acc3 = __builtin_amdgcn_mfma_f32_16x16x32_bf16(a, as_bf8(wvp[(k * 4 + 3) * 64 + lane]), acc3, 0, 0, 0);
    }
    // C/D: col = m (+16*nt), row = g*4 + reg.  Store + per-channel partial stats.
    float ps0 = 0.f, ps1 = 0.f, ps2 = 0.f, ps3 = 0.f;
    float pq0 = 0.f, pq1 = 0.f, pq2 = 0.f, pq3 = 0.f;
#pragma unroll
    for (int reg = 0; reg < 4; reg++) {
        int r = rowbase + g * 4 + reg;
        if (r < NVOX) {
            size_t b = (size_t)r * COUT + m;
            out1[b] = f2bf(acc0[reg]);
            out1[b + 16] = f2bf(acc1[reg]);
            out1[b + 32] = f2bf(acc2[reg]);
            out1[b + 48] = f2bf(acc3[reg]);
            ps0 += acc0[reg]; pq0 += acc0[reg] * acc0[reg];
            ps1 += acc1[reg]; pq1 += acc1[reg] * acc1[reg];
            ps2 += acc2[reg]; pq2 += acc2[reg] * acc2[reg];
            ps3 += acc3[reg]; pq3 += acc3[reg] * acc3[reg];
        }
    }
    atomicAdd(&ss[m], ps0);      atomicAdd(&sq[m], pq0);
    atomicAdd(&ss[m + 16], ps1); atomicAdd(&sq[m + 16], pq1);
    atomicAdd(&ss[m + 32], ps2); atomicAdd(&sq[m + 32], pq2);
    atomicAdd(&ss[m + 48], ps3); atomicAdd(&sq[m + 48], pq3);
    __syncthreads();
    if (threadIdx.x < COUT) {
        atomicAdd(&gsum2[threadIdx.x], ss[threadIdx.x]);
        atomicAdd(&gsq2[threadIdx.x], sq[threadIdx.x]);
    }
}

// ---------------- conv2: gather out1, fused bn2+relu on the fly, + residual, f32 out ------
__global__ __launch_bounds__(256) void conv2_kernel(const ushort* __restrict__ out1,
                                                    const int* __restrict__ nbr,
                                                    const ushort* __restrict__ w2s,
                                                    const float* __restrict__ x,
                                                    const ushort* __restrict__ wrs,
                                                    const float* __restrict__ bres,
                                                    const float* __restrict__ gsum2,
                                                    const float* __restrict__ gsq2,
                                                    const float* __restrict__ gamma2,
                                                    const float* __restrict__ beta2,
                                                    float* __restrict__ out) {
    const int lane = threadIdx.x & 63;
    const int wv = threadIdx.x >> 6;
    const int m = lane & 15, g = lane >> 4;
    const int rowbase = blockIdx.x * 64 + wv * 16;
    const int arow = rowbase + m;
    const bool av = arow < NVOX;
    const uint4* __restrict__ yv = (const uint4*)out1;
    const uint4* __restrict__ w2v = (const uint4*)w2s;
    const float4* __restrict__ xv = (const float4*)x;
    const uint4* __restrict__ wrv = (const uint4*)wrs;

    // bn2 params for this lane's gathered channels: half0 = g*8+j, half1 = 32+g*8+j
    float a0[8], b0[8], a1[8], b1[8];
#pragma unroll
    for (int j = 0; j < 8; j++) {
        int c = g * 8 + j;
        float mm = gsum2[c] * INVN;
        float vv = fmaxf(gsq2[c] * INVN - mm * mm, 0.f);
        a0[j] = gamma2[c] * rsqrtf(vv + EPSV);
        b0[j] = beta2[c] - mm * a0[j];
        c += 32;
        mm = gsum2[c] * INVN;
        vv = fmaxf(gsq2[c] * INVN - mm * mm, 0.f);
        a1[j] = gamma2[c] * rsqrtf(vv + EPSV);
        b1[j] = beta2[c] - mm * a1[j];
    }

    int idxs[KK];
    bool vld[KK];
#pragma unroll
    for (int k = 0; k < KK; k++) {
        int t = av ? nbr[arow * KK + k] : NVOX;
        vld[k] = (t != NVOX);
        idxs[k] = vld[k] ? t : 0;  // safe in-bounds address; result zeroed by select
    }
    constexpr int P = 6;
    uint4 ga0[P], ga1[P];
#pragma unroll
    for (int p = 0; p < P; p++) {
        ga0[p] = yv[idxs[p] * 8 + g];
        ga1[p] = yv[idxs[p] * 8 + 4 + g];
    }

    f32x4 acc0 = {0.f, 0.f, 0.f, 0.f}, acc1 = acc0, acc2 = acc0, acc3 = acc0;
#pragma unroll
    for (int k = 0; k < KK; k++) {
        bf16x8 fa0 = bn_frag(ga0[k % P], a0, b0, vld[k]);
        bf16x8 fa1 = bn_frag(ga1[k % P], a1, b1, vld[k]);
        if (k + P < KK) {
            ga0[k % P] = yv[idxs[k + P] * 8 + g];
            ga1[k % P] = yv[idxs[k + P] * 8 + 4 + g];
        }
        acc0 = __builtin_amdgcn_mfma_f32_16x16x32_bf16(fa0, as_bf8(w2v[((k * 2 + 0) * 4 + 0) * 64 + lane]), acc0, 0, 0, 0);
        acc0 = __builtin_amdgcn_mfma_f32_16x16x32_bf16(fa1, as_bf8(w2v[((k * 2 + 1) * 4 + 0) * 64 + lane]), acc0, 0, 0, 0);
        acc1 = __builtin_amdgcn_mfma_f32_16x16x32_bf16(fa0, as_bf8(w2v[((k * 2 + 0) * 4 + 1) * 64 + lane]), acc1, 0, 0, 0);
        acc1 = __builtin_amdgcn_mfma_f32_16x16x32_bf16(fa1, as_bf8(w2v[((k * 2 + 1) * 4 + 1) * 64 + lane]), acc1, 0, 0, 0);
        acc2 = __builtin_amdgcn_mfma_f32_16x16x32_bf16(fa0, as_bf8(w2v[((k * 2 + 0) * 4 + 2) * 64 + lane]), acc2, 0, 0, 0);
        acc2 = __builtin_amdgcn_mfma_f32_16x16x32_bf16(fa1, as_bf8(w2v[((k * 2 + 1) * 4 + 2) * 64 + lane]), acc2, 0, 0, 0);
        acc3 = __builtin_amdgcn_mfma_f32_16x16x32_bf16(fa0, as_bf8(w2v[((k * 2 + 0) * 4 + 3) * 64 + lane]), acc3, 0, 0, 0);
        acc3 = __builtin_amdgcn_mfma_f32_16x16x32_bf16(fa1, as_bf8(w2v[((k * 2 + 1) * 4 + 3) * 64 + lane]), acc3, 0, 0, 0);
    }
    // residual GEMM: A = x (f32 -> bf16 on the fly, K=32), B = Wres
    bf16x8 ar;
    if (av) {
        float4 f0 = xv[arow * 8 + g * 2];
        float4 f1 = xv[arow * 8 + g * 2 + 1];
        ar = f8_to_bf8(f0, f1);
    } else {
        uint4 zz = {0u, 0u, 0u, 0u};
        ar = as_bf8(zz);
    }
    acc0 = __builtin_amdgcn_mfma_f32_16x16x32_bf16(ar, as_bf8(wrv[0 * 64 + lane]), acc0, 0, 0, 0);
    acc1 = __builtin_amdgcn_mfma_f32_16x16x32_bf16(ar, as_bf8(wrv[1 * 64 + lane]), acc1, 0, 0, 0);
    acc2 = __builtin_amdgcn_mfma_f32_16x16x32_bf16(ar, as_bf8(wrv[2 * 64 + lane]), acc2, 0, 0, 0);
    acc3 = __builtin_amdgcn_mfma_f32_16x16x32_bf16(ar, as_bf8(wrv[3 * 64 + lane]), acc3, 0, 0, 0);

    float br0 = bres[m];
    float br1 = bres[16 + m];
    float br2 = bres[32 + m];
    float br3 = bres[48 + m];
#pragma unroll
    for (int reg = 0; reg < 4; reg++) {
        int r = rowbase + g * 4 + reg;
        if (r < NVOX) {
            size_t b = (size_t)r * COUT + m;
            out[b] = acc0[reg] + br0;
            out[b + 16] = acc1[reg] + br1;
            out[b + 32] = acc2[reg] + br2;
            out[b + 48] = acc3[reg] + br3;
        }
    }
}

extern "C" void kernel_launch(void* const* d_in, const int* in_sizes, int n_in,
                              void* d_out, int out_size, void* d_ws, size_t ws_size,
                              hipStream_t stream) {
    const float* x = (const float*)d_in[0];
    const int* nbr = (const int*)d_in[1];
    const float* W1 = (const float*)d_in[2];
    const float* W2 = (const float*)d_in[3];
    const float* Wres = (const float*)d_in[4];
    const float* bres = (const float*)d_in[5];
    const float* g1 = (const float*)d_in[6];
    const float* b1 = (const float*)d_in[7];
    const float* g2 = (const float*)d_in[8];
    const float* b2 = (const float*)d_in[9];
    float* out = (float*)d_out;

    // Workspace (~97 MB): y1 bf16 32MB (sentinel row N), out1 bf16 64MB (+1 pad row),
    // swizzled weights + stats < 0.5MB.
    char* ws = (char*)d_ws;
    size_t off = 0;
    auto alloc = [&](size_t bytes) -> void* {
        void* p = ws + off;
        off = (off + bytes + 255) & ~(size_t)255;
        return p;
    };
    ushort* y1 = (ushort*)alloc((size_t)(NVOX + 1) * CIN * 2);
    ushort* out1 = (ushort*)alloc((size_t)(NVOX + 1) * COUT * 2);
    ushort* w1s = (ushort*)alloc(55296 * 2);
    ushort* w2s = (ushort*)alloc(110592 * 2);
    ushort* wrs = (ushort*)alloc(2048 * 2);
    float* stats = (float*)alloc(192 * 4);
    float* sum1 = stats, *sq1 = stats + 32, *sum2 = stats + 64, *sq2 = stats + 128;

    const int convGrid = (NVOX + 63) / 64;
    const long long tot1 = (long long)NVOX * CIN / 4;

    hipLaunchKernelGGL(prep_kernel, dim3(657), dim3(256), 0, stream,
                       W1, W2, Wres, w1s, w2s, wrs, stats, y1);
    hipLaunchKernelGGL(stats1_kernel, dim3(1024), dim3(256), 0, stream,
                       (const float4*)x, tot1, sum1, sq1);
    hipLaunchKernelGGL(bn1_kernel, dim3(2048), dim3(256), 0, stream,
                       (const float4*)x, (ushort4*)y1, tot1, sum1, sq1, g1, b1);
    hipLaunchKernelGGL(conv1_kernel, dim3(convGrid), dim3(256), 0, stream,
                       y1, nbr, w1s, out1, sum2, sq2);
    hipLaunchKernelGGL(conv2_kernel, dim3(convGrid), dim3(256), 0, stream,
                       out1, nbr, w2s, x, wrs, bres, sum2, sq2, g2, b2, out);
    (void)in_sizes; (void)n_in; (void)out_size; (void)ws_size;
}